// Round 8
// baseline (1035.208 us; speedup 1.0000x reference)
//
#include <hip/hip_runtime.h>

// GINModel on MI355X (gfx950). Round 14:
//  - Round-13 post-mortem: FAST (872us) but failed post-timing determinism:
//    float atomicAdd BN stats (order varies per replay) + CSR colidx
//    permutation (fill_k atomic slot order) made outputs wobble 2.9e-3.
//  - Fixes (determinism hardening, structure unchanged):
//    (a) BN: per-block partial SLOTS (plain stores, no atomics, no zeroing);
//        bn_reduce_k reduces blocks in fixed strided order (32 blocks), then
//        bn_finalize_k sums 16 sub-partials in fixed order.
//    (b) CSR: sort_adj_k insertion-sorts each adjacency list after fill_k ->
//        neighbor sum order is content-determined, not schedule-determined.
//  - Rest identical to round 13: aggregation fused into layer kernel
//    (64-row tiles, 8 waves x 32-col slices, acc[2][4], 3 blocks/CU,
//    LDS-scratch BN reduce, setprio, kt loops unroll-1).
// fp16 internal storage, fp32 accumulation, dual-width input hardening.

typedef __attribute__((ext_vector_type(4))) float f32x4;
typedef __attribute__((ext_vector_type(8))) _Float16 f16x8;

__device__ __forceinline__ float h2f(unsigned short u) {
  _Float16 h; __builtin_memcpy(&h, &u, 2); return (float)h;
}
__device__ __forceinline__ unsigned short f2h16(float f) {
  _Float16 h = (_Float16)f; unsigned short u; __builtin_memcpy(&u, &h, 2); return u;
}
__device__ __forceinline__ unsigned short f2b(float f) {  // fp32 -> bf16 RNE
  union { float f; unsigned int i; } c; c.f = f;
  unsigned int x = c.i;
  return (unsigned short)((x + 0x7fffu + ((x >> 16) & 1u)) >> 16);
}
__device__ __forceinline__ float lin(const void* p, long long i, int wf32) {
  if (wf32) return ((const float*)p)[i];
  union { unsigned int i; float f; } c;
  c.i = ((unsigned int)((const unsigned short*)p)[i]) << 16;
  return c.f;
}
__device__ __forceinline__ int ldidx(const int* p, long long i, int w64) {
  return w64 ? p[2 * i] : p[i];
}

// flags[0]=w64 (int64 indices), flags[1]=wf32 (fp32 floats)
__global__ void detect_k(const int* __restrict__ edge, const unsigned short* __restrict__ xa,
                         int* __restrict__ flags) {
  if (threadIdx.x != 0 || blockIdx.x != 0) return;
  int nzOdd = 0;
  for (int t = 0; t < 256; t++) if (edge[2 * t + 1] != 0) nzOdd++;
  flags[0] = (nzOdd == 0) ? 1 : 0;
  int plaus = 0;
  for (int t = 0; t < 64; t++) {
    unsigned short w = xa[2 * t];
    int e = (w >> 7) & 0xFF;
    if (w == 0 || (e >= 0x70 && e <= 0x85)) plaus++;
  }
  flags[1] = (plaus < 32) ? 1 : 0;
}

__global__ void zero_i32_k(int* __restrict__ p, int n) {
  int i = blockIdx.x * blockDim.x + threadIdx.x;
  if (i < n) p[i] = 0;
}

// per-layer prep: slice 4x256 params to fp32 (no BN zeroing needed: every
// fused block writes its gsum slot unconditionally)
__global__ void prep_k(const void* __restrict__ b1, const void* __restrict__ b2,
                       const void* __restrict__ gm, const void* __restrict__ bt, int eoff,
                       float* __restrict__ pb1, float* __restrict__ pb2,
                       float* __restrict__ pg, float* __restrict__ pb,
                       const int* __restrict__ flags) {
  int wf32 = flags[1], t = threadIdx.x;
  pb1[t] = lin(b1, (long long)eoff + t, wf32);
  pb2[t] = lin(b2, (long long)eoff + t, wf32);
  pg[t]  = lin(gm, (long long)eoff + t, wf32);
  pb[t]  = lin(bt, (long long)eoff + t, wf32);
}
__global__ void copy256_k(const void* __restrict__ src, int eoff, float* __restrict__ dst,
                          const int* __restrict__ flags) {
  dst[threadIdx.x] = lin(src, (long long)eoff + threadIdx.x, flags[1]);
}

// input (R x C at element offset, dual width) -> fp16 transposed (C x R)
__global__ void transpose_off_k(const void* __restrict__ src, long long eoff,
                                unsigned short* __restrict__ dst, int R, int C,
                                const int* __restrict__ flags) {
  int wf32 = flags[1];
  __shared__ unsigned short t[32][33];
  int bx = blockIdx.x * 32, by = blockIdx.y * 32;
  int x = bx + threadIdx.x;
  for (int i = 0; i < 32; i += 8) {
    int y = by + threadIdx.y + i;
    if (y < R && x < C)
      t[threadIdx.y + i][threadIdx.x] = f2h16(lin(src, eoff + (long long)y * C + x, wf32));
  }
  __syncthreads();
  int x2 = by + threadIdx.x;
  for (int i = 0; i < 32; i += 8) {
    int y = bx + threadIdx.y + i;
    if (y < C && x2 < R) dst[(long long)y * R + x2] = t[threadIdx.x][threadIdx.y + i];
  }
}

// ---------------- CSR ----------------
__global__ void hist_k(const int* __restrict__ edge, int E, int* __restrict__ cnt,
                       const int* __restrict__ flags) {
  int w64 = flags[0];
  int e = blockIdx.x * blockDim.x + threadIdx.x;
  if (e < E) atomicAdd(&cnt[ldidx(edge, (long long)E + e, w64)], 1);
}
#define SCAN_CHUNK 1024
__global__ void scan1_k(const int* __restrict__ in, int* __restrict__ out,
                        int* __restrict__ partials, int n) {
  __shared__ int sh[256];
  int tid = threadIdx.x;
  int base = blockIdx.x * SCAN_CHUNK + tid * 4;
  int v[4]; int tsum = 0;
#pragma unroll
  for (int i = 0; i < 4; i++) { v[i] = (base + i < n) ? in[base + i] : 0; tsum += v[i]; }
  sh[tid] = tsum; __syncthreads();
  for (int off = 1; off < 256; off <<= 1) {
    int t = (tid >= off) ? sh[tid - off] : 0;
    __syncthreads();
    sh[tid] += t;
    __syncthreads();
  }
  int run = sh[tid] - tsum;
#pragma unroll
  for (int i = 0; i < 4; i++) { if (base + i < n) out[base + i] = run; run += v[i]; }
  if (tid == 255) partials[blockIdx.x] = sh[255];
}
__global__ void scan2_k(int* partials, int B) {
  __shared__ int sh[256];
  int tid = threadIdx.x;
  int orig = (tid < B) ? partials[tid] : 0;
  sh[tid] = orig; __syncthreads();
  for (int off = 1; off < 256; off <<= 1) {
    int t = (tid >= off) ? sh[tid - off] : 0;
    __syncthreads();
    sh[tid] += t;
    __syncthreads();
  }
  if (tid < B) partials[tid] = sh[tid] - orig;
}
__global__ void scan3_k(int* __restrict__ out, const int* __restrict__ partials,
                        int n, int total) {
  int base = blockIdx.x * SCAN_CHUNK + threadIdx.x * 4;
  int add = partials[blockIdx.x];
#pragma unroll
  for (int i = 0; i < 4; i++) { if (base + i < n) out[base + i] += add; }
  if (blockIdx.x == 0 && threadIdx.x == 0) out[n] = total;
}
__global__ void fill_k(const int* __restrict__ edge, int E, const int* __restrict__ rowptr,
                       int* __restrict__ cnt, int* __restrict__ colidx,
                       const int* __restrict__ flags) {
  int w64 = flags[0];
  int e = blockIdx.x * blockDim.x + threadIdx.x;
  if (e >= E) return;
  int s = ldidx(edge, e, w64);
  int d = ldidx(edge, (long long)E + e, w64);
  int p = atomicAdd(&cnt[d], 1);
  colidx[rowptr[d] + p] = s;
}
// deterministic neighbor order: insertion-sort each adjacency list (deg ~4)
__global__ void sort_adj_k(const int* __restrict__ rowptr, int* __restrict__ colidx, int Nn) {
  int i = blockIdx.x * blockDim.x + threadIdx.x;
  if (i >= Nn) return;
  int s = rowptr[i], e = rowptr[i + 1];
  for (int a = s + 1; a < e; a++) {
    int v = colidx[a]; int b = a - 1;
    while (b >= s && colidx[b] > v) { colidx[b + 1] = colidx[b]; b--; }
    colidx[b + 1] = v;
  }
}
__global__ void graph_bounds_k(const int* __restrict__ b, int Nn, int G,
                               int* __restrict__ gstart, const int* __restrict__ flags) {
  int w64 = flags[0];
  int g = blockIdx.x * blockDim.x + threadIdx.x;
  if (g > G) return;
  int lo = 0, hi = Nn;
  while (lo < hi) {
    int mid = (lo + hi) >> 1;
    if (ldidx(b, mid, w64) < g) lo = mid + 1; else hi = mid;
  }
  gstart[g] = lo;
}

// x (dual width) -> fp16
__global__ void convert_k(const void* __restrict__ x, unsigned short* __restrict__ xh,
                          long long n, const int* __restrict__ flags) {
  int wf32 = flags[1];
  long long base = ((long long)blockIdx.x * blockDim.x + threadIdx.x) * 4;
  if (base >= n) return;
#pragma unroll
  for (int k = 0; k < 4; k++) xh[base + k] = f2h16(lin(x, base + k, wf32));
}

// =====================================================================
// fused_gin_k: per-layer v = (relu(u@W1+b1))@W2 + b2, + BN column partials,
// where u[i] = hn(i) + sum_{j in nbrs(i)} hn(j), hn = APPLY? relu(v*sc+sh): v
// -- aggregation FUSED into the staging phase (no u buffer).
// One block per 64-row tile, 512 threads = 8 waves, wave owns a 32-col
// n-slice (acc[2][4] = 32 AGPRs). LDS 36KB role swap: u -> h1 -> v -> BN
// scratch. 3 blocks/CU. BN partials: per-block SLOT (plain stores, no
// atomics) -> deterministic downstream reduction.
// kt loops unroll-1 (round-9: full unroll hoists loads -> spills).
// =====================================================================
template <int KIN, int APPLY>
__global__ __launch_bounds__(512, 6) void fused_gin_k(
    const unsigned short* __restrict__ src, const float* __restrict__ scale,
    const float* __restrict__ shift, const int* __restrict__ rowptr,
    const int* __restrict__ colidx,
    const unsigned short* __restrict__ W1t, const unsigned short* __restrict__ W2t,
    const float* __restrict__ b1, const float* __restrict__ b2,
    unsigned short* __restrict__ V, int M, float* __restrict__ gsum) {
  __shared__ __align__(16) unsigned char R[36864];
  const int tid = threadIdx.x;
  const int lane = tid & 63, wave = tid >> 6;   // wave 0..7
  const int l15 = lane & 15, lq = lane >> 4;    // lq 0..3
  const int nb0 = wave * 32;                    // n-slice base (32 cols/wave)
  constexpr int KT1 = KIN / 32;                 // stage-1 k-tiles (4 or 8)
  const long long m0 = (long long)blockIdx.x * 64;

  // ---- staging: gather u-tile (64 x KIN) into R, swizzled ----
  {
    constexpr int CHUNKS = KIN / 8;             // 16B chunks per row (16 or 32)
    constexpr int ITEMS = (64 * CHUNKS) / 512;  // 2 or 4
    const int chunk = tid & (CHUNKS - 1);       // constant per thread
    const int fb = chunk * 8;
    float sc[8], sh[8];
    if (APPLY) {
#pragma unroll
      for (int k = 0; k < 8; k++) { sc[k] = scale[fb + k]; sh[k] = shift[fb + k]; }
    }
#pragma unroll
    for (int it = 0; it < ITEMS; it++) {
      int row = (tid + it * 512) / CHUNKS;      // 0..63
      long long grow = m0 + row; if (grow >= M) grow = M - 1;
      float acc[8];
      {
        uint4 raw = *(const uint4*)(src + grow * KIN + fb);
        unsigned int ws[4] = {raw.x, raw.y, raw.z, raw.w};
#pragma unroll
        for (int k = 0; k < 8; k++) {
          float xv = h2f((unsigned short)((ws[k >> 1] >> ((k & 1) * 16)) & 0xffff));
          acc[k] = APPLY ? fmaxf(xv * sc[k] + sh[k], 0.f) : xv;
        }
      }
      int s = rowptr[grow], e = rowptr[grow + 1];
      for (int j = s; j < e; j++) {
        long long nb = colidx[j];
        uint4 raw = *(const uint4*)(src + nb * KIN + fb);
        unsigned int ws[4] = {raw.x, raw.y, raw.z, raw.w};
#pragma unroll
        for (int k = 0; k < 8; k++) {
          float xv = h2f((unsigned short)((ws[k >> 1] >> ((k & 1) * 16)) & 0xffff));
          acc[k] += APPLY ? fmaxf(xv * sc[k] + sh[k], 0.f) : xv;
        }
      }
      uint4 o; unsigned int wo[4];
#pragma unroll
      for (int p = 0; p < 4; p++)
        wo[p] = (unsigned int)f2h16(acc[2 * p]) | ((unsigned int)f2h16(acc[2 * p + 1]) << 16);
      o.x = wo[0]; o.y = wo[1]; o.z = wo[2]; o.w = wo[3];
      *(uint4*)(R + row * (2 * KIN) + 16 * (chunk ^ (row & 7))) = o;
    }
  }
  __syncthreads();  // u-tile resident

  // ---- stage 1: h1T[n][m] = relu((u @ W1)^T + b1) ----
  f32x4 acc[2][4] = {};
  __builtin_amdgcn_s_setprio(1);
#pragma unroll 1
  for (int kt = 0; kt < KT1; kt++) {
    f16x8 wf[2], uf[4];
#pragma unroll
    for (int r = 0; r < 2; r++)
      wf[r] = *(const f16x8*)(W1t + (long long)(nb0 + 16 * r + l15) * KIN + kt * 32 + lq * 8);
#pragma unroll
    for (int c = 0; c < 4; c++) {
      int m = 16 * c + l15;
      uf[c] = *(const f16x8*)(R + m * (2 * KIN) + 16 * ((kt * 4 + lq) ^ (m & 7)));
    }
#pragma unroll
    for (int r = 0; r < 2; r++)
#pragma unroll
      for (int c = 0; c < 4; c++)
        acc[r][c] = __builtin_amdgcn_mfma_f32_16x16x32_f16(wf[r], uf[c], acc[r][c], 0, 0, 0);
  }
  __builtin_amdgcn_s_setprio(0);
  __syncthreads();  // bar1: all stage-1 reads of u done
  // h1 -> R (row m, 512B stride, swizzled); bias + relu
#pragma unroll
  for (int r = 0; r < 2; r++) {
    int nbase = nb0 + 16 * r + lq * 4;
    float4 bv = *(const float4*)(b1 + nbase);
#pragma unroll
    for (int c = 0; c < 4; c++) {
      int m = 16 * c + l15;
      unsigned int h0 = f2h16(fmaxf(acc[r][c][0] + bv.x, 0.f));
      unsigned int h1v = f2h16(fmaxf(acc[r][c][1] + bv.y, 0.f));
      unsigned int h2v = f2h16(fmaxf(acc[r][c][2] + bv.z, 0.f));
      unsigned int h3 = f2h16(fmaxf(acc[r][c][3] + bv.w, 0.f));
      uint2 pk; pk.x = h0 | (h1v << 16); pk.y = h2v | (h3 << 16);
      int by = m * 512 + 16 * ((nbase >> 3) ^ (m & 7)) + ((nbase & 7) << 1);
      *(uint2*)(R + by) = pk;
    }
  }
  __syncthreads();  // bar2: h1 visible
  // ---- stage 2: vT[n][m] = (h1 @ W2)^T + b2 ----
  f32x4 acc2[2][4] = {};
  __builtin_amdgcn_s_setprio(1);
#pragma unroll 1
  for (int kt = 0; kt < 8; kt++) {
    f16x8 wf[2], hf[4];
#pragma unroll
    for (int r = 0; r < 2; r++)
      wf[r] = *(const f16x8*)(W2t + (long long)(nb0 + 16 * r + l15) * 256 + kt * 32 + lq * 8);
#pragma unroll
    for (int c = 0; c < 4; c++) {
      int m = 16 * c + l15;
      hf[c] = *(const f16x8*)(R + m * 512 + 16 * ((kt * 4 + lq) ^ (m & 7)));
    }
#pragma unroll
    for (int r = 0; r < 2; r++)
#pragma unroll
      for (int c = 0; c < 4; c++)
        acc2[r][c] = __builtin_amdgcn_mfma_f32_16x16x32_f16(wf[r], hf[c], acc2[r][c], 0, 0, 0);
  }
  __builtin_amdgcn_s_setprio(0);
  __syncthreads();  // bar3: all stage-2 reads of h1 done
  // v -> R ([m][n], swizzled); bias, no relu
#pragma unroll
  for (int r = 0; r < 2; r++) {
    int nbase = nb0 + 16 * r + lq * 4;
    float4 bv = *(const float4*)(b2 + nbase);
#pragma unroll
    for (int c = 0; c < 4; c++) {
      int m = 16 * c + l15;
      unsigned int h0 = f2h16(acc2[r][c][0] + bv.x);
      unsigned int h1v = f2h16(acc2[r][c][1] + bv.y);
      unsigned int h2v = f2h16(acc2[r][c][2] + bv.z);
      unsigned int h3 = f2h16(acc2[r][c][3] + bv.w);
      uint2 pk; pk.x = h0 | (h1v << 16); pk.y = h2v | (h3 << 16);
      int by = m * 512 + 16 * ((nbase >> 3) ^ (m & 7)) + ((nbase & 7) << 1);
      *(uint2*)(R + by) = pk;
    }
  }
  __syncthreads();  // bar4: v tile complete
  // coalesced store + BN partials. thread (c32, rg): rows rg*4..+3, cols c32*8..+7
  const int c32 = tid & 31, rg = tid >> 5;
  float s8[8] = {}, q8[8] = {};
#pragma unroll
  for (int k = 0; k < 4; k++) {
    int m = rg * 4 + k;
    uint4 vw = *(const uint4*)(R + m * 512 + 16 * (c32 ^ (m & 7)));
    long long grow = m0 + m;
    if (grow < M) {
      *(uint4*)(V + grow * 256 + c32 * 8) = vw;
      unsigned int ws[4] = {vw.x, vw.y, vw.z, vw.w};
#pragma unroll
      for (int kk = 0; kk < 8; kk++) {
        float xv = h2f((unsigned short)((ws[kk >> 1] >> ((kk & 1) * 16)) & 0xffff));
        s8[kk] += xv; q8[kk] += xv * xv;
      }
    }
  }
  __syncthreads();  // bar5: v reads done; R reusable as scratch
  float* shf = (float*)R;  // [256][17] sums + [256][17] sumsq = 34816 B
#pragma unroll
  for (int kk = 0; kk < 8; kk++) {
    int col = c32 * 8 + kk;
    shf[col * 17 + rg] = s8[kk];
    shf[4352 + col * 17 + rg] = q8[kk];
  }
  __syncthreads();  // bar6
  // per-block slot: plain stores, fixed in-block reduction order -> deterministic
  float* gb = gsum + (long long)blockIdx.x * 512;
  if (tid < 256) {
    float tot = 0.f;
#pragma unroll
    for (int g = 0; g < 16; g++) tot += shf[tid * 17 + g];
    gb[tid] = tot;
  } else {
    int col = tid - 256; float tot = 0.f;
#pragma unroll
    for (int g = 0; g < 16; g++) tot += shf[4352 + col * 17 + g];
    gb[256 + col] = tot;
  }
}

// stage A of deterministic BN reduce: partial[c*16+sub] = sum over blocks
// b = sub, sub+16, ... (fixed order). c in [0,512).
__global__ void bn_reduce_k(const float* __restrict__ gsum, int nblocks,
                            float* __restrict__ partial) {
  int gid = blockIdx.x * blockDim.x + threadIdx.x;  // 0..8191
  if (gid >= 512 * 16) return;
  int c = gid >> 4, sub = gid & 15;
  float t = 0.f;
  for (int b = sub; b < nblocks; b += 16) t += gsum[(long long)b * 512 + c];
  partial[c * 16 + sub] = t;
}

__global__ void bn_finalize_k(const float* __restrict__ partial,
                              const float* __restrict__ pg, const float* __restrict__ pb,
                              int Nn, float* __restrict__ scale, float* __restrict__ shift) {
  int f = threadIdx.x;
  float s = 0.f, q = 0.f;
#pragma unroll
  for (int sub = 0; sub < 16; sub++) {
    s += partial[f * 16 + sub];
    q += partial[(256 + f) * 16 + sub];
  }
  float inv = 1.f / (float)Nn;
  float mean = s * inv;
  float var = fmaxf(q * inv - mean * mean, 0.f);
  float sc = pg[f] * rsqrtf(var + 1e-5f);
  scale[f] = sc;
  shift[f] = pb[f] - mean * sc;
}

// MFMA fp16 GEMM (predictor only). Tile 128x128, BK=32, 4 waves.
#define SA 40    // padded A/B staging stride (fp16)
#define SP 136   // padded C-tile stride (fp16)
__global__ __launch_bounds__(256) void gemm_k(
    const unsigned short* __restrict__ A, const unsigned short* __restrict__ Bt,
    const float* __restrict__ bias, unsigned short* __restrict__ C,
    int M, int K, int relu) {
  __shared__ __align__(16) unsigned short smem[128 * SP];
  unsigned short* As = smem;
  unsigned short* Bs = smem + 128 * SA;
  int m0 = blockIdx.x * 128, n0 = blockIdx.y * 128;
  int tid = threadIdx.x;
  int wave = tid >> 6, lane = tid & 63;
  int wm = (wave >> 1) * 64, wnn = (wave & 1) * 64;
  int lrow = lane & 15, lqq = lane >> 4;
  f32x4 acc[4][4] = {};
  int ktiles = K >> 5;
  int srow = tid >> 2;
  int ch8 = (tid & 3) << 3;
  int rowA0 = m0 + srow;      rowA0 = rowA0 < M ? rowA0 : M - 1;
  int rowA1 = m0 + srow + 64; rowA1 = rowA1 < M ? rowA1 : M - 1;
  const unsigned short* pa0 = A + (long long)rowA0 * K + ch8;
  const unsigned short* pa1 = A + (long long)rowA1 * K + ch8;
  const unsigned short* pq0 = Bt + (long long)(n0 + srow) * K + ch8;
  const unsigned short* pq1 = Bt + (long long)(n0 + srow + 64) * K + ch8;
  uint4 va0 = *(const uint4*)pa0, va1 = *(const uint4*)pa1;
  uint4 vb0 = *(const uint4*)pq0, vb1 = *(const uint4*)pq1;
  int lo0 = srow * SA + ch8, lo1 = (srow + 64) * SA + ch8;
  for (int kt = 0; kt < ktiles; ++kt) {
    __syncthreads();
    *(uint4*)(As + lo0) = va0;
    *(uint4*)(As + lo1) = va1;
    *(uint4*)(Bs + lo0) = vb0;
    *(uint4*)(Bs + lo1) = vb1;
    __syncthreads();
    f16x8 af[4], bf[4];
#pragma unroll
    for (int r = 0; r < 4; r++)
      af[r] = *(const f16x8*)(As + (wm + 16 * r + lrow) * SA + lqq * 8);
#pragma unroll
    for (int c = 0; c < 4; c++)
      bf[c] = *(const f16x8*)(Bs + (wnn + 16 * c + lrow) * SA + lqq * 8);
    if (kt + 1 < ktiles) {
      int kb = (kt + 1) << 5;
      va0 = *(const uint4*)(pa0 + kb); va1 = *(const uint4*)(pa1 + kb);
      vb0 = *(const uint4*)(pq0 + kb); vb1 = *(const uint4*)(pq1 + kb);
    }
#pragma unroll
    for (int r = 0; r < 4; r++)
#pragma unroll
      for (int c = 0; c < 4; c++)
        acc[r][c] = __builtin_amdgcn_mfma_f32_16x16x32_f16(af[r], bf[c], acc[r][c], 0, 0, 0);
  }
  __syncthreads();
  unsigned short* Ct = smem;
#pragma unroll
  for (int c = 0; c < 4; c++) {
    int col = wnn + 16 * c + lrow;
    float bv = bias[n0 + col];
#pragma unroll
    for (int r = 0; r < 4; r++) {
      int rbase = wm + 16 * r + lqq * 4;
#pragma unroll
      for (int i = 0; i < 4; i++) {
        float v = acc[r][c][i] + bv;
        if (relu) v = fmaxf(v, 0.f);
        Ct[(rbase + i) * SP + col] = f2h16(v);
      }
    }
  }
  __syncthreads();
  int c16 = tid & 15, g = tid >> 4;
#pragma unroll
  for (int i = 0; i < 8; i++) {
    int row = g + i * 16;
    int grow = m0 + row;
    if (grow < M) {
      uint4 vw = *(const uint4*)(Ct + row * SP + c16 * 8);
      *(uint4*)(C + (long long)grow * 256 + n0 + c16 * 8) = vw;
    }
  }
}

// fused pool: mean over graph rows of relu(v*sc+sh)
__global__ void pool_fused_k(const unsigned short* __restrict__ v, const float* __restrict__ scale,
                             const float* __restrict__ shift, const int* __restrict__ gstart,
                             unsigned short* __restrict__ gout) {
  int g = blockIdx.x, f = threadIdx.x;
  int s = gstart[g], e = gstart[g + 1];
  float sc = scale[f], sh = shift[f];
  float acc = 0.f;
  for (int r = s; r < e; r++) acc += fmaxf(h2f(v[(long long)r * 256 + f]) * sc + sh, 0.f);
  gout[(long long)g * 256 + f] = f2h16(acc / fmaxf((float)(e - s), 1.f));
}
__global__ void pred2_k(const unsigned short* __restrict__ p1, const void* __restrict__ Wp2,
                        const void* __restrict__ bp2, void* __restrict__ out, int G,
                        const int* __restrict__ flags) {
  int wf32 = flags[1];
  int idx = blockIdx.x * blockDim.x + threadIdx.x;
  if (idx >= G * 12) return;
  int g = idx / 12, t = idx - g * 12;
  float acc = lin(bp2, t, wf32);
  const unsigned short* row = p1 + (long long)g * 256;
  for (int k = 0; k < 256; k++) acc += h2f(row[k]) * lin(Wp2, k * 12 + t, wf32);
  if (wf32) ((float*)out)[idx] = acc;
  else      ((unsigned short*)out)[idx] = f2b(acc);
}

extern "C" void kernel_launch(void* const* d_in, const int* in_sizes, int n_in,
                              void* d_out, int out_size, void* d_ws, size_t ws_size,
                              hipStream_t stream) {
  int wb = -1;
  for (int i = 3; i + 15 < n_in; i++) {
    if (in_sizes[i] == 32768 && in_sizes[i + 1] == 256 && in_sizes[i + 2] == 65536 &&
        in_sizes[i + 3] == 256 && in_sizes[i + 4] == 256 && in_sizes[i + 5] == 256 &&
        in_sizes[i + 6] == 262144) { wb = i; break; }
  }
  if (wb < 0) wb = (n_in >= 20) ? 4 : 3;

  const void* x      = d_in[0];
  const int*  edge   = (const int*)d_in[1];
  const int*  batch  = (const int*)d_in[2];
  const void* W1_0   = d_in[wb + 0];
  const void* b1_0   = d_in[wb + 1];
  const void* W2_0   = d_in[wb + 2];
  const void* b2_0   = d_in[wb + 3];
  const void* gamma0 = d_in[wb + 4];
  const void* beta0  = d_in[wb + 5];
  const void* W1s    = d_in[wb + 6];
  const void* b1s    = d_in[wb + 7];
  const void* W2s    = d_in[wb + 8];
  const void* b2s    = d_in[wb + 9];
  const void* gammas = d_in[wb + 10];
  const void* betas  = d_in[wb + 11];
  const void* Wp1    = d_in[wb + 12];
  const void* bp1    = d_in[wb + 13];
  const void* Wp2    = d_in[wb + 14];
  const void* bp2    = d_in[wb + 15];

  const int N = in_sizes[0] / 128;
  const int E = in_sizes[1] / 2;
  const int G = out_size / 12;
  const int H = 256;
  const int ntiles = (N + 63) / 64;

  char* w = (char*)d_ws;
  size_t off = 0;
  auto alloc = [&](size_t bytes) -> char* {
    char* p = w + off;
    off += (bytes + 255) & ~(size_t)255;
    return p;
  };
  unsigned short* bufX  = (unsigned short*)alloc((size_t)N * H * 2);
  unsigned short* bufY  = (unsigned short*)alloc((size_t)N * H * 2);  // xh parks here first
  unsigned short* w1_0t = (unsigned short*)alloc((size_t)128 * 256 * 2);
  unsigned short* w2_0t = (unsigned short*)alloc((size_t)256 * 256 * 2);
  unsigned short* w1st  = (unsigned short*)alloc((size_t)4 * 256 * 256 * 2);
  unsigned short* w2st  = (unsigned short*)alloc((size_t)4 * 256 * 256 * 2);
  unsigned short* wp1t  = (unsigned short*)alloc((size_t)256 * 256 * 2);
  int*   rowptr   = (int*)alloc((size_t)(N + 1) * 4);
  int*   cnt      = (int*)alloc((size_t)N * 4);
  int*   colidx   = (int*)alloc((size_t)E * 4);
  int*   partials = (int*)alloc(1024 * 4);
  float* gsum     = (float*)alloc((size_t)ntiles * 512 * 4);  // per-block BN slots
  float* bnpart   = (float*)alloc(512 * 16 * 4);              // reduce stage A out
  float* bnscale  = (float*)alloc(256 * 4);
  float* bnshift  = (float*)alloc(256 * 4);
  float* pg       = (float*)alloc(256 * 4);
  float* pb       = (float*)alloc(256 * 4);
  float* pb1      = (float*)alloc(256 * 4);
  float* pb2      = (float*)alloc(256 * 4);
  int*   gstart   = (int*)alloc((size_t)(G + 1) * 4);
  int*   flags    = (int*)alloc(256);
  unsigned short* gpool = (unsigned short*)alloc((size_t)G * H * 2);
  unsigned short* p1    = (unsigned short*)alloc((size_t)G * H * 2);
  (void)ws_size; (void)n_in;

  detect_k<<<1, 64, 0, stream>>>(edge, (const unsigned short*)x, flags);

  // x -> fp16 into bufY (read by layer-0 fused kernel; dead after)
  convert_k<<<(int)(((long long)N * 128 / 4 + 255) / 256), 256, 0, stream>>>(
      x, bufY, (long long)N * 128, flags);

  dim3 tb(32, 8);
  auto transpose = [&](const void* src, long long eoff, unsigned short* dst, int R, int C) {
    transpose_off_k<<<dim3((C + 31) / 32, (R + 31) / 32), tb, 0, stream>>>(src, eoff, dst, R, C, flags);
  };
  transpose(W1_0, 0, w1_0t, 128, 256);
  transpose(W2_0, 0, w2_0t, 256, 256);
  for (int i = 0; i < 4; i++) {
    transpose(W1s, (long long)i * 65536, w1st + i * 65536, 256, 256);
    transpose(W2s, (long long)i * 65536, w2st + i * 65536, 256, 256);
  }
  transpose(Wp1, 0, wp1t, 256, 256);

  // CSR (precedes layer 0: aggregation fused into layer kernel).
  // sort_adj_k makes neighbor order content-determined (replay-deterministic).
  zero_i32_k<<<(N + 255) / 256, 256, 0, stream>>>(cnt, N);
  hist_k<<<(E + 255) / 256, 256, 0, stream>>>(edge, E, cnt, flags);
  int NB = (N + SCAN_CHUNK - 1) / SCAN_CHUNK;
  scan1_k<<<NB, 256, 0, stream>>>(cnt, rowptr, partials, N);
  scan2_k<<<1, 256, 0, stream>>>(partials, NB);
  scan3_k<<<NB, 256, 0, stream>>>(rowptr, partials, N, E);
  zero_i32_k<<<(N + 255) / 256, 256, 0, stream>>>(cnt, N);
  fill_k<<<(E + 255) / 256, 256, 0, stream>>>(edge, E, rowptr, cnt, colidx, flags);
  sort_adj_k<<<(N + 255) / 256, 256, 0, stream>>>(rowptr, colidx, N);
  graph_bounds_k<<<(G + 1 + 255) / 256, 256, 0, stream>>>(batch, N, G, gstart, flags);

  auto bn_reduce = [&]() {
    bn_reduce_k<<<32, 256, 0, stream>>>(gsum, ntiles, bnpart);
    bn_finalize_k<<<1, 256, 0, stream>>>(bnpart, pg, pb, N, bnscale, bnshift);
  };

  // ---- layer 0: u = x + sum(nbr x); v0 -> bufX ----
  prep_k<<<1, 256, 0, stream>>>(b1_0, b2_0, gamma0, beta0, 0, pb1, pb2, pg, pb, flags);
  fused_gin_k<128, 0><<<ntiles, 512, 0, stream>>>(
      bufY, bnscale, bnshift, rowptr, colidx, w1_0t, w2_0t, pb1, pb2, bufX, N, gsum);
  bn_reduce();
  unsigned short* cur = bufX;  // pre-BN v0
  unsigned short* oth = bufY;
  // ---- layers 1..4: u = hn(v_prev) aggregated; v_i -> oth ----
  for (int i = 0; i < 4; i++) {
    prep_k<<<1, 256, 0, stream>>>(b1s, b2s, gammas, betas, i * 256, pb1, pb2, pg, pb, flags);
    fused_gin_k<256, 1><<<ntiles, 512, 0, stream>>>(
        cur, bnscale, bnshift, rowptr, colidx, w1st + i * 65536, w2st + i * 65536,
        pb1, pb2, oth, N, gsum);
    bn_reduce();
    unsigned short* t = cur; cur = oth; oth = t;  // v_i now in cur
  }

  // ---- pool + predictor ----
  copy256_k<<<1, 256, 0, stream>>>(bp1, 0, pb1, flags);
  pool_fused_k<<<G, 256, 0, stream>>>(cur, bnscale, bnshift, gstart, gpool);
  gemm_k<<<dim3((G + 127) / 128, 2), 256, 0, stream>>>(gpool, wp1t, pb1, p1, G, 256, 1);
  pred2_k<<<(G * 12 + 255) / 256, 256, 0, stream>>>(p1, Wp2, bp2, d_out, G, flags);
}

// Round 9
// 974.559 us; speedup vs baseline: 1.0622x; 1.0622x over previous
//
#include <hip/hip_runtime.h>

// GINModel on MI355X (gfx950). Round 15:
//  - Round-14 post-mortem: determinism fixes cost ~160us; culprit is
//    bn_reduce_k's strided access (thread loads 32KB apart, lanes 2KB apart
//    -> ~800K uncoalesced 4B loads, ~25-30us x5). Fix: contiguous-chunk
//    coalesced deterministic 2-stage reduce (bn_reduceA_k 64 blocks summing
//    sequential row ranges, thread-per-column -> 2KB contiguous per iter;
//    bn_finalB_k sums 64 partials in fixed order + finalizes).
//  - Everything else byte-identical to round 14 (isolated change).
// fp16 internal storage, fp32 accumulation, dual-width input hardening.

typedef __attribute__((ext_vector_type(4))) float f32x4;
typedef __attribute__((ext_vector_type(8))) _Float16 f16x8;

__device__ __forceinline__ float h2f(unsigned short u) {
  _Float16 h; __builtin_memcpy(&h, &u, 2); return (float)h;
}
__device__ __forceinline__ unsigned short f2h16(float f) {
  _Float16 h = (_Float16)f; unsigned short u; __builtin_memcpy(&u, &h, 2); return u;
}
__device__ __forceinline__ unsigned short f2b(float f) {  // fp32 -> bf16 RNE
  union { float f; unsigned int i; } c; c.f = f;
  unsigned int x = c.i;
  return (unsigned short)((x + 0x7fffu + ((x >> 16) & 1u)) >> 16);
}
__device__ __forceinline__ float lin(const void* p, long long i, int wf32) {
  if (wf32) return ((const float*)p)[i];
  union { unsigned int i; float f; } c;
  c.i = ((unsigned int)((const unsigned short*)p)[i]) << 16;
  return c.f;
}
__device__ __forceinline__ int ldidx(const int* p, long long i, int w64) {
  return w64 ? p[2 * i] : p[i];
}

// flags[0]=w64 (int64 indices), flags[1]=wf32 (fp32 floats)
__global__ void detect_k(const int* __restrict__ edge, const unsigned short* __restrict__ xa,
                         int* __restrict__ flags) {
  if (threadIdx.x != 0 || blockIdx.x != 0) return;
  int nzOdd = 0;
  for (int t = 0; t < 256; t++) if (edge[2 * t + 1] != 0) nzOdd++;
  flags[0] = (nzOdd == 0) ? 1 : 0;
  int plaus = 0;
  for (int t = 0; t < 64; t++) {
    unsigned short w = xa[2 * t];
    int e = (w >> 7) & 0xFF;
    if (w == 0 || (e >= 0x70 && e <= 0x85)) plaus++;
  }
  flags[1] = (plaus < 32) ? 1 : 0;
}

__global__ void zero_i32_k(int* __restrict__ p, int n) {
  int i = blockIdx.x * blockDim.x + threadIdx.x;
  if (i < n) p[i] = 0;
}

// per-layer prep: slice 4x256 params to fp32 (no BN zeroing needed: every
// fused block writes its gsum slot unconditionally)
__global__ void prep_k(const void* __restrict__ b1, const void* __restrict__ b2,
                       const void* __restrict__ gm, const void* __restrict__ bt, int eoff,
                       float* __restrict__ pb1, float* __restrict__ pb2,
                       float* __restrict__ pg, float* __restrict__ pb,
                       const int* __restrict__ flags) {
  int wf32 = flags[1], t = threadIdx.x;
  pb1[t] = lin(b1, (long long)eoff + t, wf32);
  pb2[t] = lin(b2, (long long)eoff + t, wf32);
  pg[t]  = lin(gm, (long long)eoff + t, wf32);
  pb[t]  = lin(bt, (long long)eoff + t, wf32);
}
__global__ void copy256_k(const void* __restrict__ src, int eoff, float* __restrict__ dst,
                          const int* __restrict__ flags) {
  dst[threadIdx.x] = lin(src, (long long)eoff + threadIdx.x, flags[1]);
}

// input (R x C at element offset, dual width) -> fp16 transposed (C x R)
__global__ void transpose_off_k(const void* __restrict__ src, long long eoff,
                                unsigned short* __restrict__ dst, int R, int C,
                                const int* __restrict__ flags) {
  int wf32 = flags[1];
  __shared__ unsigned short t[32][33];
  int bx = blockIdx.x * 32, by = blockIdx.y * 32;
  int x = bx + threadIdx.x;
  for (int i = 0; i < 32; i += 8) {
    int y = by + threadIdx.y + i;
    if (y < R && x < C)
      t[threadIdx.y + i][threadIdx.x] = f2h16(lin(src, eoff + (long long)y * C + x, wf32));
  }
  __syncthreads();
  int x2 = by + threadIdx.x;
  for (int i = 0; i < 32; i += 8) {
    int y = bx + threadIdx.y + i;
    if (y < C && x2 < R) dst[(long long)y * R + x2] = t[threadIdx.x][threadIdx.y + i];
  }
}

// ---------------- CSR ----------------
__global__ void hist_k(const int* __restrict__ edge, int E, int* __restrict__ cnt,
                       const int* __restrict__ flags) {
  int w64 = flags[0];
  int e = blockIdx.x * blockDim.x + threadIdx.x;
  if (e < E) atomicAdd(&cnt[ldidx(edge, (long long)E + e, w64)], 1);
}
#define SCAN_CHUNK 1024
__global__ void scan1_k(const int* __restrict__ in, int* __restrict__ out,
                        int* __restrict__ partials, int n) {
  __shared__ int sh[256];
  int tid = threadIdx.x;
  int base = blockIdx.x * SCAN_CHUNK + tid * 4;
  int v[4]; int tsum = 0;
#pragma unroll
  for (int i = 0; i < 4; i++) { v[i] = (base + i < n) ? in[base + i] : 0; tsum += v[i]; }
  sh[tid] = tsum; __syncthreads();
  for (int off = 1; off < 256; off <<= 1) {
    int t = (tid >= off) ? sh[tid - off] : 0;
    __syncthreads();
    sh[tid] += t;
    __syncthreads();
  }
  int run = sh[tid] - tsum;
#pragma unroll
  for (int i = 0; i < 4; i++) { if (base + i < n) out[base + i] = run; run += v[i]; }
  if (tid == 255) partials[blockIdx.x] = sh[255];
}
__global__ void scan2_k(int* partials, int B) {
  __shared__ int sh[256];
  int tid = threadIdx.x;
  int orig = (tid < B) ? partials[tid] : 0;
  sh[tid] = orig; __syncthreads();
  for (int off = 1; off < 256; off <<= 1) {
    int t = (tid >= off) ? sh[tid - off] : 0;
    __syncthreads();
    sh[tid] += t;
    __syncthreads();
  }
  if (tid < B) partials[tid] = sh[tid] - orig;
}
__global__ void scan3_k(int* __restrict__ out, const int* __restrict__ partials,
                        int n, int total) {
  int base = blockIdx.x * SCAN_CHUNK + threadIdx.x * 4;
  int add = partials[blockIdx.x];
#pragma unroll
  for (int i = 0; i < 4; i++) { if (base + i < n) out[base + i] += add; }
  if (blockIdx.x == 0 && threadIdx.x == 0) out[n] = total;
}
__global__ void fill_k(const int* __restrict__ edge, int E, const int* __restrict__ rowptr,
                       int* __restrict__ cnt, int* __restrict__ colidx,
                       const int* __restrict__ flags) {
  int w64 = flags[0];
  int e = blockIdx.x * blockDim.x + threadIdx.x;
  if (e >= E) return;
  int s = ldidx(edge, e, w64);
  int d = ldidx(edge, (long long)E + e, w64);
  int p = atomicAdd(&cnt[d], 1);
  colidx[rowptr[d] + p] = s;
}
// deterministic neighbor order: insertion-sort each adjacency list (deg ~4)
__global__ void sort_adj_k(const int* __restrict__ rowptr, int* __restrict__ colidx, int Nn) {
  int i = blockIdx.x * blockDim.x + threadIdx.x;
  if (i >= Nn) return;
  int s = rowptr[i], e = rowptr[i + 1];
  for (int a = s + 1; a < e; a++) {
    int v = colidx[a]; int b = a - 1;
    while (b >= s && colidx[b] > v) { colidx[b + 1] = colidx[b]; b--; }
    colidx[b + 1] = v;
  }
}
__global__ void graph_bounds_k(const int* __restrict__ b, int Nn, int G,
                               int* __restrict__ gstart, const int* __restrict__ flags) {
  int w64 = flags[0];
  int g = blockIdx.x * blockDim.x + threadIdx.x;
  if (g > G) return;
  int lo = 0, hi = Nn;
  while (lo < hi) {
    int mid = (lo + hi) >> 1;
    if (ldidx(b, mid, w64) < g) lo = mid + 1; else hi = mid;
  }
  gstart[g] = lo;
}

// x (dual width) -> fp16
__global__ void convert_k(const void* __restrict__ x, unsigned short* __restrict__ xh,
                          long long n, const int* __restrict__ flags) {
  int wf32 = flags[1];
  long long base = ((long long)blockIdx.x * blockDim.x + threadIdx.x) * 4;
  if (base >= n) return;
#pragma unroll
  for (int k = 0; k < 4; k++) xh[base + k] = f2h16(lin(x, base + k, wf32));
}

// =====================================================================
// fused_gin_k: per-layer v = (relu(u@W1+b1))@W2 + b2, + BN column partials,
// where u[i] = hn(i) + sum_{j in nbrs(i)} hn(j), hn = APPLY? relu(v*sc+sh): v
// -- aggregation FUSED into the staging phase (no u buffer).
// One block per 64-row tile, 512 threads = 8 waves, wave owns a 32-col
// n-slice (acc[2][4] = 32 AGPRs). LDS 36KB role swap: u -> h1 -> v -> BN
// scratch. 3 blocks/CU. BN partials: per-block SLOT (plain stores, no
// atomics) -> deterministic downstream reduction.
// kt loops unroll-1 (round-9: full unroll hoists loads -> spills).
// =====================================================================
template <int KIN, int APPLY>
__global__ __launch_bounds__(512, 6) void fused_gin_k(
    const unsigned short* __restrict__ src, const float* __restrict__ scale,
    const float* __restrict__ shift, const int* __restrict__ rowptr,
    const int* __restrict__ colidx,
    const unsigned short* __restrict__ W1t, const unsigned short* __restrict__ W2t,
    const float* __restrict__ b1, const float* __restrict__ b2,
    unsigned short* __restrict__ V, int M, float* __restrict__ gsum) {
  __shared__ __align__(16) unsigned char R[36864];
  const int tid = threadIdx.x;
  const int lane = tid & 63, wave = tid >> 6;   // wave 0..7
  const int l15 = lane & 15, lq = lane >> 4;    // lq 0..3
  const int nb0 = wave * 32;                    // n-slice base (32 cols/wave)
  constexpr int KT1 = KIN / 32;                 // stage-1 k-tiles (4 or 8)
  const long long m0 = (long long)blockIdx.x * 64;

  // ---- staging: gather u-tile (64 x KIN) into R, swizzled ----
  {
    constexpr int CHUNKS = KIN / 8;             // 16B chunks per row (16 or 32)
    constexpr int ITEMS = (64 * CHUNKS) / 512;  // 2 or 4
    const int chunk = tid & (CHUNKS - 1);       // constant per thread
    const int fb = chunk * 8;
    float sc[8], sh[8];
    if (APPLY) {
#pragma unroll
      for (int k = 0; k < 8; k++) { sc[k] = scale[fb + k]; sh[k] = shift[fb + k]; }
    }
#pragma unroll
    for (int it = 0; it < ITEMS; it++) {
      int row = (tid + it * 512) / CHUNKS;      // 0..63
      long long grow = m0 + row; if (grow >= M) grow = M - 1;
      float acc[8];
      {
        uint4 raw = *(const uint4*)(src + grow * KIN + fb);
        unsigned int ws[4] = {raw.x, raw.y, raw.z, raw.w};
#pragma unroll
        for (int k = 0; k < 8; k++) {
          float xv = h2f((unsigned short)((ws[k >> 1] >> ((k & 1) * 16)) & 0xffff));
          acc[k] = APPLY ? fmaxf(xv * sc[k] + sh[k], 0.f) : xv;
        }
      }
      int s = rowptr[grow], e = rowptr[grow + 1];
      for (int j = s; j < e; j++) {
        long long nb = colidx[j];
        uint4 raw = *(const uint4*)(src + nb * KIN + fb);
        unsigned int ws[4] = {raw.x, raw.y, raw.z, raw.w};
#pragma unroll
        for (int k = 0; k < 8; k++) {
          float xv = h2f((unsigned short)((ws[k >> 1] >> ((k & 1) * 16)) & 0xffff));
          acc[k] += APPLY ? fmaxf(xv * sc[k] + sh[k], 0.f) : xv;
        }
      }
      uint4 o; unsigned int wo[4];
#pragma unroll
      for (int p = 0; p < 4; p++)
        wo[p] = (unsigned int)f2h16(acc[2 * p]) | ((unsigned int)f2h16(acc[2 * p + 1]) << 16);
      o.x = wo[0]; o.y = wo[1]; o.z = wo[2]; o.w = wo[3];
      *(uint4*)(R + row * (2 * KIN) + 16 * (chunk ^ (row & 7))) = o;
    }
  }
  __syncthreads();  // u-tile resident

  // ---- stage 1: h1T[n][m] = relu((u @ W1)^T + b1) ----
  f32x4 acc[2][4] = {};
  __builtin_amdgcn_s_setprio(1);
#pragma unroll 1
  for (int kt = 0; kt < KT1; kt++) {
    f16x8 wf[2], uf[4];
#pragma unroll
    for (int r = 0; r < 2; r++)
      wf[r] = *(const f16x8*)(W1t + (long long)(nb0 + 16 * r + l15) * KIN + kt * 32 + lq * 8);
#pragma unroll
    for (int c = 0; c < 4; c++) {
      int m = 16 * c + l15;
      uf[c] = *(const f16x8*)(R + m * (2 * KIN) + 16 * ((kt * 4 + lq) ^ (m & 7)));
    }
#pragma unroll
    for (int r = 0; r < 2; r++)
#pragma unroll
      for (int c = 0; c < 4; c++)
        acc[r][c] = __builtin_amdgcn_mfma_f32_16x16x32_f16(wf[r], uf[c], acc[r][c], 0, 0, 0);
  }
  __builtin_amdgcn_s_setprio(0);
  __syncthreads();  // bar1: all stage-1 reads of u done
  // h1 -> R (row m, 512B stride, swizzled); bias + relu
#pragma unroll
  for (int r = 0; r < 2; r++) {
    int nbase = nb0 + 16 * r + lq * 4;
    float4 bv = *(const float4*)(b1 + nbase);
#pragma unroll
    for (int c = 0; c < 4; c++) {
      int m = 16 * c + l15;
      unsigned int h0 = f2h16(fmaxf(acc[r][c][0] + bv.x, 0.f));
      unsigned int h1v = f2h16(fmaxf(acc[r][c][1] + bv.y, 0.f));
      unsigned int h2v = f2h16(fmaxf(acc[r][c][2] + bv.z, 0.f));
      unsigned int h3 = f2h16(fmaxf(acc[r][c][3] + bv.w, 0.f));
      uint2 pk; pk.x = h0 | (h1v << 16); pk.y = h2v | (h3 << 16);
      int by = m * 512 + 16 * ((nbase >> 3) ^ (m & 7)) + ((nbase & 7) << 1);
      *(uint2*)(R + by) = pk;
    }
  }
  __syncthreads();  // bar2: h1 visible
  // ---- stage 2: vT[n][m] = (h1 @ W2)^T + b2 ----
  f32x4 acc2[2][4] = {};
  __builtin_amdgcn_s_setprio(1);
#pragma unroll 1
  for (int kt = 0; kt < 8; kt++) {
    f16x8 wf[2], hf[4];
#pragma unroll
    for (int r = 0; r < 2; r++)
      wf[r] = *(const f16x8*)(W2t + (long long)(nb0 + 16 * r + l15) * 256 + kt * 32 + lq * 8);
#pragma unroll
    for (int c = 0; c < 4; c++) {
      int m = 16 * c + l15;
      hf[c] = *(const f16x8*)(R + m * 512 + 16 * ((kt * 4 + lq) ^ (m & 7)));
    }
#pragma unroll
    for (int r = 0; r < 2; r++)
#pragma unroll
      for (int c = 0; c < 4; c++)
        acc2[r][c] = __builtin_amdgcn_mfma_f32_16x16x32_f16(wf[r], hf[c], acc2[r][c], 0, 0, 0);
  }
  __builtin_amdgcn_s_setprio(0);
  __syncthreads();  // bar3: all stage-2 reads of h1 done
  // v -> R ([m][n], swizzled); bias, no relu
#pragma unroll
  for (int r = 0; r < 2; r++) {
    int nbase = nb0 + 16 * r + lq * 4;
    float4 bv = *(const float4*)(b2 + nbase);
#pragma unroll
    for (int c = 0; c < 4; c++) {
      int m = 16 * c + l15;
      unsigned int h0 = f2h16(acc2[r][c][0] + bv.x);
      unsigned int h1v = f2h16(acc2[r][c][1] + bv.y);
      unsigned int h2v = f2h16(acc2[r][c][2] + bv.z);
      unsigned int h3 = f2h16(acc2[r][c][3] + bv.w);
      uint2 pk; pk.x = h0 | (h1v << 16); pk.y = h2v | (h3 << 16);
      int by = m * 512 + 16 * ((nbase >> 3) ^ (m & 7)) + ((nbase & 7) << 1);
      *(uint2*)(R + by) = pk;
    }
  }
  __syncthreads();  // bar4: v tile complete
  // coalesced store + BN partials. thread (c32, rg): rows rg*4..+3, cols c32*8..+7
  const int c32 = tid & 31, rg = tid >> 5;
  float s8[8] = {}, q8[8] = {};
#pragma unroll
  for (int k = 0; k < 4; k++) {
    int m = rg * 4 + k;
    uint4 vw = *(const uint4*)(R + m * 512 + 16 * (c32 ^ (m & 7)));
    long long grow = m0 + m;
    if (grow < M) {
      *(uint4*)(V + grow * 256 + c32 * 8) = vw;
      unsigned int ws[4] = {vw.x, vw.y, vw.z, vw.w};
#pragma unroll
      for (int kk = 0; kk < 8; kk++) {
        float xv = h2f((unsigned short)((ws[kk >> 1] >> ((kk & 1) * 16)) & 0xffff));
        s8[kk] += xv; q8[kk] += xv * xv;
      }
    }
  }
  __syncthreads();  // bar5: v reads done; R reusable as scratch
  float* shf = (float*)R;  // [256][17] sums + [256][17] sumsq = 34816 B
#pragma unroll
  for (int kk = 0; kk < 8; kk++) {
    int col = c32 * 8 + kk;
    shf[col * 17 + rg] = s8[kk];
    shf[4352 + col * 17 + rg] = q8[kk];
  }
  __syncthreads();  // bar6
  // per-block slot: plain stores, fixed in-block reduction order -> deterministic
  float* gb = gsum + (long long)blockIdx.x * 512;
  if (tid < 256) {
    float tot = 0.f;
#pragma unroll
    for (int g = 0; g < 16; g++) tot += shf[tid * 17 + g];
    gb[tid] = tot;
  } else {
    int col = tid - 256; float tot = 0.f;
#pragma unroll
    for (int g = 0; g < 16; g++) tot += shf[4352 + col * 17 + g];
    gb[256 + col] = tot;
  }
}

// deterministic BN reduce, stage A (COALESCED): block p sums gsum rows
// [p*per, min((p+1)*per, nblocks)) sequentially; thread t owns column t.
// Each iteration reads 2KB contiguous (512 threads x 4B).
__global__ void bn_reduceA_k(const float* __restrict__ gsum, int nblocks,
                             float* __restrict__ part) {
  int p = blockIdx.x, t = threadIdx.x;
  int per = (nblocks + gridDim.x - 1) / gridDim.x;
  int b0 = p * per, b1 = b0 + per;
  if (b1 > nblocks) b1 = nblocks;
  float acc = 0.f;
  for (int b = b0; b < b1; b++) acc += gsum[(long long)b * 512 + t];
  part[(long long)p * 512 + t] = acc;
}
// stage B: sum 64 partials in fixed order (coalesced) + finalize scale/shift
__global__ void bn_finalB_k(const float* __restrict__ part, int nparts,
                            const float* __restrict__ pg, const float* __restrict__ pb,
                            int Nn, float* __restrict__ scale, float* __restrict__ shift) {
  __shared__ float sh[512];
  int t = threadIdx.x;
  float acc = 0.f;
  for (int p = 0; p < nparts; p++) acc += part[(long long)p * 512 + t];
  sh[t] = acc;
  __syncthreads();
  if (t < 256) {
    float s = sh[t], q = sh[256 + t];
    float inv = 1.f / (float)Nn;
    float mean = s * inv;
    float var = fmaxf(q * inv - mean * mean, 0.f);
    float sc = pg[t] * rsqrtf(var + 1e-5f);
    scale[t] = sc;
    shift[t] = pb[t] - mean * sc;
  }
}

// MFMA fp16 GEMM (predictor only). Tile 128x128, BK=32, 4 waves.
#define SA 40    // padded A/B staging stride (fp16)
#define SP 136   // padded C-tile stride (fp16)
__global__ __launch_bounds__(256) void gemm_k(
    const unsigned short* __restrict__ A, const unsigned short* __restrict__ Bt,
    const float* __restrict__ bias, unsigned short* __restrict__ C,
    int M, int K, int relu) {
  __shared__ __align__(16) unsigned short smem[128 * SP];
  unsigned short* As = smem;
  unsigned short* Bs = smem + 128 * SA;
  int m0 = blockIdx.x * 128, n0 = blockIdx.y * 128;
  int tid = threadIdx.x;
  int wave = tid >> 6, lane = tid & 63;
  int wm = (wave >> 1) * 64, wnn = (wave & 1) * 64;
  int lrow = lane & 15, lqq = lane >> 4;
  f32x4 acc[4][4] = {};
  int ktiles = K >> 5;
  int srow = tid >> 2;
  int ch8 = (tid & 3) << 3;
  int rowA0 = m0 + srow;      rowA0 = rowA0 < M ? rowA0 : M - 1;
  int rowA1 = m0 + srow + 64; rowA1 = rowA1 < M ? rowA1 : M - 1;
  const unsigned short* pa0 = A + (long long)rowA0 * K + ch8;
  const unsigned short* pa1 = A + (long long)rowA1 * K + ch8;
  const unsigned short* pq0 = Bt + (long long)(n0 + srow) * K + ch8;
  const unsigned short* pq1 = Bt + (long long)(n0 + srow + 64) * K + ch8;
  uint4 va0 = *(const uint4*)pa0, va1 = *(const uint4*)pa1;
  uint4 vb0 = *(const uint4*)pq0, vb1 = *(const uint4*)pq1;
  int lo0 = srow * SA + ch8, lo1 = (srow + 64) * SA + ch8;
  for (int kt = 0; kt < ktiles; ++kt) {
    __syncthreads();
    *(uint4*)(As + lo0) = va0;
    *(uint4*)(As + lo1) = va1;
    *(uint4*)(Bs + lo0) = vb0;
    *(uint4*)(Bs + lo1) = vb1;
    __syncthreads();
    f16x8 af[4], bf[4];
#pragma unroll
    for (int r = 0; r < 4; r++)
      af[r] = *(const f16x8*)(As + (wm + 16 * r + lrow) * SA + lqq * 8);
#pragma unroll
    for (int c = 0; c < 4; c++)
      bf[c] = *(const f16x8*)(Bs + (wnn + 16 * c + lrow) * SA + lqq * 8);
    if (kt + 1 < ktiles) {
      int kb = (kt + 1) << 5;
      va0 = *(const uint4*)(pa0 + kb); va1 = *(const uint4*)(pa1 + kb);
      vb0 = *(const uint4*)(pq0 + kb); vb1 = *(const uint4*)(pq1 + kb);
    }
#pragma unroll
    for (int r = 0; r < 4; r++)
#pragma unroll
      for (int c = 0; c < 4; c++)
        acc[r][c] = __builtin_amdgcn_mfma_f32_16x16x32_f16(af[r], bf[c], acc[r][c], 0, 0, 0);
  }
  __syncthreads();
  unsigned short* Ct = smem;
#pragma unroll
  for (int c = 0; c < 4; c++) {
    int col = wnn + 16 * c + lrow;
    float bv = bias[n0 + col];
#pragma unroll
    for (int r = 0; r < 4; r++) {
      int rbase = wm + 16 * r + lqq * 4;
#pragma unroll
      for (int i = 0; i < 4; i++) {
        float v = acc[r][c][i] + bv;
        if (relu) v = fmaxf(v, 0.f);
        Ct[(rbase + i) * SP + col] = f2h16(v);
      }
    }
  }
  __syncthreads();
  int c16 = tid & 15, g = tid >> 4;
#pragma unroll
  for (int i = 0; i < 8; i++) {
    int row = g + i * 16;
    int grow = m0 + row;
    if (grow < M) {
      uint4 vw = *(const uint4*)(Ct + row * SP + c16 * 8);
      *(uint4*)(C + (long long)grow * 256 + n0 + c16 * 8) = vw;
    }
  }
}

// fused pool: mean over graph rows of relu(v*sc+sh)
__global__ void pool_fused_k(const unsigned short* __restrict__ v, const float* __restrict__ scale,
                             const float* __restrict__ shift, const int* __restrict__ gstart,
                             unsigned short* __restrict__ gout) {
  int g = blockIdx.x, f = threadIdx.x;
  int s = gstart[g], e = gstart[g + 1];
  float sc = scale[f], sh = shift[f];
  float acc = 0.f;
  for (int r = s; r < e; r++) acc += fmaxf(h2f(v[(long long)r * 256 + f]) * sc + sh, 0.f);
  gout[(long long)g * 256 + f] = f2h16(acc / fmaxf((float)(e - s), 1.f));
}
__global__ void pred2_k(const unsigned short* __restrict__ p1, const void* __restrict__ Wp2,
                        const void* __restrict__ bp2, void* __restrict__ out, int G,
                        const int* __restrict__ flags) {
  int wf32 = flags[1];
  int idx = blockIdx.x * blockDim.x + threadIdx.x;
  if (idx >= G * 12) return;
  int g = idx / 12, t = idx - g * 12;
  float acc = lin(bp2, t, wf32);
  const unsigned short* row = p1 + (long long)g * 256;
  for (int k = 0; k < 256; k++) acc += h2f(row[k]) * lin(Wp2, k * 12 + t, wf32);
  if (wf32) ((float*)out)[idx] = acc;
  else      ((unsigned short*)out)[idx] = f2b(acc);
}

extern "C" void kernel_launch(void* const* d_in, const int* in_sizes, int n_in,
                              void* d_out, int out_size, void* d_ws, size_t ws_size,
                              hipStream_t stream) {
  int wb = -1;
  for (int i = 3; i + 15 < n_in; i++) {
    if (in_sizes[i] == 32768 && in_sizes[i + 1] == 256 && in_sizes[i + 2] == 65536 &&
        in_sizes[i + 3] == 256 && in_sizes[i + 4] == 256 && in_sizes[i + 5] == 256 &&
        in_sizes[i + 6] == 262144) { wb = i; break; }
  }
  if (wb < 0) wb = (n_in >= 20) ? 4 : 3;

  const void* x      = d_in[0];
  const int*  edge   = (const int*)d_in[1];
  const int*  batch  = (const int*)d_in[2];
  const void* W1_0   = d_in[wb + 0];
  const void* b1_0   = d_in[wb + 1];
  const void* W2_0   = d_in[wb + 2];
  const void* b2_0   = d_in[wb + 3];
  const void* gamma0 = d_in[wb + 4];
  const void* beta0  = d_in[wb + 5];
  const void* W1s    = d_in[wb + 6];
  const void* b1s    = d_in[wb + 7];
  const void* W2s    = d_in[wb + 8];
  const void* b2s    = d_in[wb + 9];
  const void* gammas = d_in[wb + 10];
  const void* betas  = d_in[wb + 11];
  const void* Wp1    = d_in[wb + 12];
  const void* bp1    = d_in[wb + 13];
  const void* Wp2    = d_in[wb + 14];
  const void* bp2    = d_in[wb + 15];

  const int N = in_sizes[0] / 128;
  const int E = in_sizes[1] / 2;
  const int G = out_size / 12;
  const int H = 256;
  const int ntiles = (N + 63) / 64;

  char* w = (char*)d_ws;
  size_t off = 0;
  auto alloc = [&](size_t bytes) -> char* {
    char* p = w + off;
    off += (bytes + 255) & ~(size_t)255;
    return p;
  };
  unsigned short* bufX  = (unsigned short*)alloc((size_t)N * H * 2);
  unsigned short* bufY  = (unsigned short*)alloc((size_t)N * H * 2);  // xh parks here first
  unsigned short* w1_0t = (unsigned short*)alloc((size_t)128 * 256 * 2);
  unsigned short* w2_0t = (unsigned short*)alloc((size_t)256 * 256 * 2);
  unsigned short* w1st  = (unsigned short*)alloc((size_t)4 * 256 * 256 * 2);
  unsigned short* w2st  = (unsigned short*)alloc((size_t)4 * 256 * 256 * 2);
  unsigned short* wp1t  = (unsigned short*)alloc((size_t)256 * 256 * 2);
  int*   rowptr   = (int*)alloc((size_t)(N + 1) * 4);
  int*   cnt      = (int*)alloc((size_t)N * 4);
  int*   colidx   = (int*)alloc((size_t)E * 4);
  int*   partials = (int*)alloc(1024 * 4);
  float* gsum     = (float*)alloc((size_t)ntiles * 512 * 4);  // per-block BN slots
  float* bnpart   = (float*)alloc(64 * 512 * 4);              // reduce stage A out
  float* bnscale  = (float*)alloc(256 * 4);
  float* bnshift  = (float*)alloc(256 * 4);
  float* pg       = (float*)alloc(256 * 4);
  float* pb       = (float*)alloc(256 * 4);
  float* pb1      = (float*)alloc(256 * 4);
  float* pb2      = (float*)alloc(256 * 4);
  int*   gstart   = (int*)alloc((size_t)(G + 1) * 4);
  int*   flags    = (int*)alloc(256);
  unsigned short* gpool = (unsigned short*)alloc((size_t)G * H * 2);
  unsigned short* p1    = (unsigned short*)alloc((size_t)G * H * 2);
  (void)ws_size; (void)n_in;

  detect_k<<<1, 64, 0, stream>>>(edge, (const unsigned short*)x, flags);

  // x -> fp16 into bufY (read by layer-0 fused kernel; dead after)
  convert_k<<<(int)(((long long)N * 128 / 4 + 255) / 256), 256, 0, stream>>>(
      x, bufY, (long long)N * 128, flags);

  dim3 tb(32, 8);
  auto transpose = [&](const void* src, long long eoff, unsigned short* dst, int R, int C) {
    transpose_off_k<<<dim3((C + 31) / 32, (R + 31) / 32), tb, 0, stream>>>(src, eoff, dst, R, C, flags);
  };
  transpose(W1_0, 0, w1_0t, 128, 256);
  transpose(W2_0, 0, w2_0t, 256, 256);
  for (int i = 0; i < 4; i++) {
    transpose(W1s, (long long)i * 65536, w1st + i * 65536, 256, 256);
    transpose(W2s, (long long)i * 65536, w2st + i * 65536, 256, 256);
  }
  transpose(Wp1, 0, wp1t, 256, 256);

  // CSR (precedes layer 0: aggregation fused into layer kernel).
  // sort_adj_k makes neighbor order content-determined (replay-deterministic).
  zero_i32_k<<<(N + 255) / 256, 256, 0, stream>>>(cnt, N);
  hist_k<<<(E + 255) / 256, 256, 0, stream>>>(edge, E, cnt, flags);
  int NB = (N + SCAN_CHUNK - 1) / SCAN_CHUNK;
  scan1_k<<<NB, 256, 0, stream>>>(cnt, rowptr, partials, N);
  scan2_k<<<1, 256, 0, stream>>>(partials, NB);
  scan3_k<<<NB, 256, 0, stream>>>(rowptr, partials, N, E);
  zero_i32_k<<<(N + 255) / 256, 256, 0, stream>>>(cnt, N);
  fill_k<<<(E + 255) / 256, 256, 0, stream>>>(edge, E, rowptr, cnt, colidx, flags);
  sort_adj_k<<<(N + 255) / 256, 256, 0, stream>>>(rowptr, colidx, N);
  graph_bounds_k<<<(G + 1 + 255) / 256, 256, 0, stream>>>(batch, N, G, gstart, flags);

  auto bn_reduce = [&]() {
    bn_reduceA_k<<<64, 512, 0, stream>>>(gsum, ntiles, bnpart);
    bn_finalB_k<<<1, 512, 0, stream>>>(bnpart, 64, pg, pb, N, bnscale, bnshift);
  };

  // ---- layer 0: u = x + sum(nbr x); v0 -> bufX ----
  prep_k<<<1, 256, 0, stream>>>(b1_0, b2_0, gamma0, beta0, 0, pb1, pb2, pg, pb, flags);
  fused_gin_k<128, 0><<<ntiles, 512, 0, stream>>>(
      bufY, bnscale, bnshift, rowptr, colidx, w1_0t, w2_0t, pb1, pb2, bufX, N, gsum);
  bn_reduce();
  unsigned short* cur = bufX;  // pre-BN v0
  unsigned short* oth = bufY;
  // ---- layers 1..4: u = hn(v_prev) aggregated; v_i -> oth ----
  for (int i = 0; i < 4; i++) {
    prep_k<<<1, 256, 0, stream>>>(b1s, b2s, gammas, betas, i * 256, pb1, pb2, pg, pb, flags);
    fused_gin_k<256, 1><<<ntiles, 512, 0, stream>>>(
        cur, bnscale, bnshift, rowptr, colidx, w1st + i * 65536, w2st + i * 65536,
        pb1, pb2, oth, N, gsum);
    bn_reduce();
    unsigned short* t = cur; cur = oth; oth = t;  // v_i now in cur
  }

  // ---- pool + predictor ----
  copy256_k<<<1, 256, 0, stream>>>(bp1, 0, pb1, flags);
  pool_fused_k<<<G, 256, 0, stream>>>(cur, bnscale, bnshift, gstart, gpool);
  gemm_k<<<dim3((G + 127) / 128, 2), 256, 0, stream>>>(gpool, wp1t, pb1, p1, G, 256, 1);
  pred2_k<<<(G * 12 + 255) / 256, 256, 0, stream>>>(p1, Wp2, bp2, d_out, G, flags);
}